// Round 13
// baseline (274.622 us; speedup 1.0000x reference)
//
#include <hip/hip_runtime.h>
#include <hip/hip_fp16.h>

#define NNODES 100000
#define NB 391         // coarse buckets: node >> 8 (256 nodes each); 99999>>8 = 390
#define BSHIFT 8
#define BMASK 255
#define BCAP 4608      // per-bucket capacity (avg 4092, sigma ~64 -> +8 sigma)
#define WT_LD 136      // padded k-stride (halves) for transposed W1

typedef _Float16 half8 __attribute__((ext_vector_type(8)));
typedef float floatx4 __attribute__((ext_vector_type(4)));

// ---- phase A: coarse-bin edges; rank = histogram atomic return (4 edges/thread) ----
__global__ void binA_kernel(const int* __restrict__ src, const int* __restrict__ dst,
                            int* __restrict__ bcnt, unsigned* __restrict__ bdata, int E) {
    __shared__ int hist[NB];
    __shared__ int gb[NB];
    const int BATCH = 1024;  // 4 edges / thread
    for (int base = blockIdx.x * BATCH; base < E; base += gridDim.x * BATCH) {
        for (int i = threadIdx.x; i < NB; i += blockDim.x) hist[i] = 0;
        __syncthreads();
        int s[4], d[4], rank[4];
        int cnt = 0;
        if (base + BATCH <= E) {  // full batch: one int4 load
            int4 sv = ((const int4*)(src + base))[threadIdx.x];
            int4 dv = ((const int4*)(dst + base))[threadIdx.x];
            s[0] = sv.x; d[0] = dv.x; rank[0] = atomicAdd(&hist[dv.x >> BSHIFT], 1);
            s[1] = sv.y; d[1] = dv.y; rank[1] = atomicAdd(&hist[dv.y >> BSHIFT], 1);
            s[2] = sv.z; d[2] = dv.z; rank[2] = atomicAdd(&hist[dv.z >> BSHIFT], 1);
            s[3] = sv.w; d[3] = dv.w; rank[3] = atomicAdd(&hist[dv.w >> BSHIFT], 1);
            cnt = 4;
        } else {
#pragma unroll
            for (int k = 0; k < 4; ++k) {
                int idx = base + k * 256 + threadIdx.x;
                if (idx < E) {
                    s[cnt] = src[idx];
                    d[cnt] = dst[idx];
                    rank[cnt] = atomicAdd(&hist[d[cnt] >> BSHIFT], 1);
                    ++cnt;
                }
            }
        }
        __syncthreads();
        for (int i = threadIdx.x; i < NB; i += blockDim.x) {
            int c = hist[i];
            gb[i] = (c > 0) ? atomicAdd(&bcnt[i], c) : 0;
        }
        __syncthreads();
        for (int k = 0; k < cnt; ++k) {
            int b = d[k] >> BSHIFT;
            int lo = gb[b] + rank[k];
            if (lo < BCAP)
                bdata[(size_t)b * BCAP + lo] = ((unsigned)s[k] << BSHIFT) | ((unsigned)d[k] & BMASK);
        }
        __syncthreads();
    }
}

// ---- fused prep: block 0 = bucket scan, block 1 = w23 fold, block 2 = W1 transpose/fp16 ----
__global__ __launch_bounds__(1024) void prep_kernel(
        const int* __restrict__ bcnt, int* __restrict__ bstart,
        const float* __restrict__ W2, const float* __restrict__ b2,
        const float* __restrict__ W3, float* __restrict__ w23,
        const float* __restrict__ W1, __half* __restrict__ Wt) {
    if (blockIdx.x == 0) {
        __shared__ int sh[NB];
        int t = threadIdx.x;
        if (t < NB) sh[t] = min(bcnt[t], BCAP);
        __syncthreads();
        if (t == 0) {
            int acc = 0;
            for (int i = 0; i < NB; ++i) { int v = sh[i]; sh[i] = acc; acc += v; }
        }
        __syncthreads();
        if (t < NB) bstart[t] = sh[t];
    } else if (blockIdx.x == 1) {
        int k = threadIdx.x;
        if (k < 71) {
            float a = 0.f;
            for (int j = 0; j < 82; ++j) a += W2[k * 82 + j] * W3[j];
            w23[k] = a;
        } else if (k == 71) {
            float a = 0.f;
            for (int j = 0; j < 82; ++j) a += b2[j] * W3[j];
            w23[71] = a;
        }
    } else {
        for (int i = threadIdx.x; i < 80 * WT_LD; i += blockDim.x) {
            int nn = i / WT_LD, k = i - nn * WT_LD;
            float v = (nn < 71 && k < 128) ? W1[k * 71 + nn] : 0.f;
            Wt[i] = __float2half(v);
        }
    }
}

// ---- phase B: per-bucket (256 nodes) LDS-cached hist(+rank) + scan + CSR fill ----
__global__ __launch_bounds__(512) void binB2_kernel(
        const int* __restrict__ bcnt, const int* __restrict__ bstart,
        const unsigned* __restrict__ bdata,
        int* __restrict__ deg, int* __restrict__ end_off, float* __restrict__ dinv,
        int* __restrict__ csr, int n) {
    __shared__ unsigned edata[BCAP];       // 18 KB
    __shared__ unsigned short rankb[BCAP]; // 9 KB
    __shared__ int hist[256];
    __shared__ int nstart[256];
    __shared__ int wsum[4];
    int b = blockIdx.x;
    int tid = threadIdx.x;
    int cnt = min(bcnt[b], BCAP);
    int base = bstart[b];
    const unsigned* p = bdata + (size_t)b * BCAP;
    if (tid < 256) hist[tid] = 0;
    __syncthreads();
    for (int i = tid; i < cnt; i += 512) {
        unsigned e = p[i];
        edata[i] = e;
        rankb[i] = (unsigned short)atomicAdd(&hist[e & BMASK], 1);
    }
    __syncthreads();
    if (tid < 256) {  // 4-wave inclusive scan of hist
        int v = hist[tid];
        int lane = tid & 63;
        int incl = v;
#pragma unroll
        for (int off = 1; off < 64; off <<= 1) {
            int t = __shfl_up(incl, off);
            if (lane >= off) incl += t;
        }
        nstart[tid] = incl;  // stash inclusive intra-wave prefix
        if (lane == 63) wsum[tid >> 6] = incl;
    }
    __syncthreads();
    if (tid == 0) {
        int acc = 0;
#pragma unroll
        for (int w = 0; w < 4; ++w) { int t = wsum[w]; wsum[w] = acc; acc += t; }
    }
    __syncthreads();
    if (tid < 256) {
        int v = hist[tid];
        int start = base + wsum[tid >> 6] + nstart[tid] - v;  // exclusive prefix
        int node = (b << BSHIFT) + tid;
        if (node < n) {
            deg[node] = v;
            end_off[node] = start + v;
            dinv[node] = rsqrtf((float)v + 1.0f);
        }
        nstart[tid] = start;
    }
    __syncthreads();
    for (int i = tid; i < cnt; i += 512) {
        unsigned e = edata[i];
        int pos = nstart[e & BMASK] + (int)rankb[i];
        csr[pos] = (int)(e >> BSHIFT);
    }
}

// ---- MFMA transform: msg[row, 0..71] = half( (x[row,:128] @ W1) * scale[row] ) ----
__global__ __launch_bounds__(256) void xform_mfma(
        const float* __restrict__ x, const __half* __restrict__ Wt,
        const float* __restrict__ scale, __half* __restrict__ msg, int n) {
    __shared__ __half Wsh[80 * WT_LD];   // 21.25 KB
    {
        const uint4* sp = (const uint4*)Wt;
        uint4* dp = (uint4*)Wsh;
        for (int i = threadIdx.x; i < (80 * WT_LD * 2) / 16; i += blockDim.x) dp[i] = sp[i];
    }
    __syncthreads();
    int lane = threadIdx.x & 63;
    int m = lane & 15, q = lane >> 4;
    int gw = (blockIdx.x * blockDim.x + threadIdx.x) >> 6;
    int nw = (gridDim.x * blockDim.x) >> 6;
    int nrt = n >> 4;  // 16-row tiles (n % 16 == 0)
    for (int rt = gw; rt < nrt; rt += nw) {
        int rb = rt << 4;
        const float* xr = x + (size_t)(rb + m) * 128 + q * 8;
        floatx4 acc[5];
#pragma unroll
        for (int t = 0; t < 5; ++t) acc[t] = (floatx4){0.f, 0.f, 0.f, 0.f};
#pragma unroll
        for (int ks = 0; ks < 4; ++ks) {
            float4 f0 = *(const float4*)(xr + ks * 32);
            float4 f1 = *(const float4*)(xr + ks * 32 + 4);
            half8 a;
            a[0] = (_Float16)f0.x; a[1] = (_Float16)f0.y;
            a[2] = (_Float16)f0.z; a[3] = (_Float16)f0.w;
            a[4] = (_Float16)f1.x; a[5] = (_Float16)f1.y;
            a[6] = (_Float16)f1.z; a[7] = (_Float16)f1.w;
#pragma unroll
            for (int t = 0; t < 5; ++t) {
                half8 b = *(const half8*)&Wsh[(t * 16 + m) * WT_LD + ks * 32 + q * 8];
                acc[t] = __builtin_amdgcn_mfma_f32_16x16x32_f16(a, b, acc[t], 0, 0, 0);
            }
        }
        float sc[4];
#pragma unroll
        for (int r = 0; r < 4; ++r) sc[r] = scale[rb + q * 4 + r];
#pragma unroll
        for (int t = 0; t < 5; ++t) {
            int col = t * 16 + m;
            if (col < 72) {
#pragma unroll
                for (int r = 0; r < 4; ++r)
                    msg[(size_t)(rb + q * 4 + r) * 72 + col] = __float2half(acc[t][r] * sc[r]);
            }
        }
    }
}

// ---- fused gather + ReLU + w23 contraction: wave per node, 8-edge unroll ----
template <int OC>
__global__ void gather_fused(const __half2* __restrict__ msg, const int* __restrict__ csr,
                             const int* __restrict__ end_off, const int* __restrict__ deg,
                             const float* __restrict__ dinv, const float* __restrict__ b,
                             const float* __restrict__ w23, float* __restrict__ g2, int n) {
    constexpr int OC2 = (OC + 1) / 2;
    int lane = threadIdx.x & 63;
    int wid = (blockIdx.x * blockDim.x + threadIdx.x) >> 6;
    int nwaves = (gridDim.x * blockDim.x) >> 6;
    bool act = lane < OC2;
    int c = lane << 1;
    float bx = (act && c < OC) ? b[c] : 0.f;
    float by = (act && c + 1 < OC) ? b[c + 1] : 0.f;
    float w0 = (act && c < OC) ? w23[c] : 0.f;
    float w1 = (act && c + 1 < OC) ? w23[c + 1] : 0.f;
    for (int node = wid; node < n; node += nwaves) {
        int end = end_off[node];
        int cnt = deg[node];
        int start = end - cnt;
        float ax0 = 0.f, ay0 = 0.f, ax1 = 0.f, ay1 = 0.f;
        float ax2 = 0.f, ay2 = 0.f, ax3 = 0.f, ay3 = 0.f;
        for (int base = 0; base < cnt; base += 64) {
            int rem = min(cnt - base, 64);
            int se = (lane < rem) ? csr[start + base + lane] : 0;
            int j = 0;
            for (; j + 7 < rem; j += 8) {
                int s0 = __shfl(se, j),     s1 = __shfl(se, j + 1);
                int s2 = __shfl(se, j + 2), s3 = __shfl(se, j + 3);
                int s4 = __shfl(se, j + 4), s5 = __shfl(se, j + 5);
                int s6 = __shfl(se, j + 6), s7 = __shfl(se, j + 7);
                if (act) {
                    float2 v0 = __half22float2(msg[(size_t)s0 * OC2 + lane]);
                    float2 v1 = __half22float2(msg[(size_t)s1 * OC2 + lane]);
                    float2 v2 = __half22float2(msg[(size_t)s2 * OC2 + lane]);
                    float2 v3 = __half22float2(msg[(size_t)s3 * OC2 + lane]);
                    float2 v4 = __half22float2(msg[(size_t)s4 * OC2 + lane]);
                    float2 v5 = __half22float2(msg[(size_t)s5 * OC2 + lane]);
                    float2 v6 = __half22float2(msg[(size_t)s6 * OC2 + lane]);
                    float2 v7 = __half22float2(msg[(size_t)s7 * OC2 + lane]);
                    ax0 += v0.x; ay0 += v0.y;  ax1 += v1.x; ay1 += v1.y;
                    ax2 += v2.x; ay2 += v2.y;  ax3 += v3.x; ay3 += v3.y;
                    ax0 += v4.x; ay0 += v4.y;  ax1 += v5.x; ay1 += v5.y;
                    ax2 += v6.x; ay2 += v6.y;  ax3 += v7.x; ay3 += v7.y;
                }
            }
            for (; j + 3 < rem; j += 4) {
                int s0 = __shfl(se, j),     s1 = __shfl(se, j + 1);
                int s2 = __shfl(se, j + 2), s3 = __shfl(se, j + 3);
                if (act) {
                    float2 v0 = __half22float2(msg[(size_t)s0 * OC2 + lane]);
                    float2 v1 = __half22float2(msg[(size_t)s1 * OC2 + lane]);
                    float2 v2 = __half22float2(msg[(size_t)s2 * OC2 + lane]);
                    float2 v3 = __half22float2(msg[(size_t)s3 * OC2 + lane]);
                    ax0 += v0.x; ay0 += v0.y;  ax1 += v1.x; ay1 += v1.y;
                    ax2 += v2.x; ay2 += v2.y;  ax3 += v3.x; ay3 += v3.y;
                }
            }
            for (; j < rem; ++j) {
                int s = __shfl(se, j);
                if (act) {
                    float2 v = __half22float2(msg[(size_t)s * OC2 + lane]);
                    ax0 += v.x; ay0 += v.y;
                }
            }
        }
        float dv = dinv[node];
        float p = 0.f;
        if (act) {
            float2 selfv = __half22float2(msg[(size_t)node * OC2 + lane]);
            float sx = ((ax0 + ax1) + (ax2 + ax3)) + selfv.x;
            float sy = ((ay0 + ay1) + (ay2 + ay3)) + selfv.y;
            float vx = fmaxf(dv * sx + bx, 0.f);   // ReLU
            float vy = fmaxf(dv * sy + by, 0.f);
            p = vx * w0 + vy * w1;
        }
#pragma unroll
        for (int off = 32; off > 0; off >>= 1) p += __shfl_down(p, off);
        if (lane == 0) g2[node] = dv * p;
    }
}

// ---- scalar gather 1: q[i] = dinv_i * ( dinv_i*(sum g2[src] + g2[i]) + bw ) ----
__global__ void sgather_q(const float* __restrict__ g2, const int* __restrict__ csr,
                          const int* __restrict__ end_off, const int* __restrict__ deg,
                          const float* __restrict__ dinv, const float* __restrict__ w23,
                          float* __restrict__ q, int n) {
    float bw = w23[71];
    int stride = gridDim.x * blockDim.x;
    for (int i = blockIdx.x * blockDim.x + threadIdx.x; i < n; i += stride) {
        int end = end_off[i];
        int cnt = deg[i];
        float acc = 0.f;
        for (int j = end - cnt; j < end; ++j) acc += g2[csr[j]];
        float dv = dinv[i];
        q[i] = dv * (dv * (acc + g2[i]) + bw);
    }
}

// ---- scalar gather 2: out[i] = dinv_i*(sum q[src] + q[i]) + b3 ----
__global__ void sgather_out(const float* __restrict__ q, const int* __restrict__ csr,
                            const int* __restrict__ end_off, const int* __restrict__ deg,
                            const float* __restrict__ dinv, const float* __restrict__ b3,
                            float* __restrict__ out, int n) {
    int stride = gridDim.x * blockDim.x;
    for (int i = blockIdx.x * blockDim.x + threadIdx.x; i < n; i += stride) {
        int end = end_off[i];
        int cnt = deg[i];
        float acc = 0.f;
        for (int j = end - cnt; j < end; ++j) acc += q[csr[j]];
        out[i] = dinv[i] * (acc + q[i]) + b3[0];
    }
}

extern "C" void kernel_launch(void* const* d_in, const int* in_sizes, int n_in,
                              void* d_out, int out_size, void* d_ws, size_t ws_size,
                              hipStream_t stream) {
    const float* x  = (const float*)d_in[0];
    const int*   ei = (const int*)d_in[1];
    const float* W1 = (const float*)d_in[2];
    const float* b1 = (const float*)d_in[3];
    const float* W2 = (const float*)d_in[4];
    const float* b2 = (const float*)d_in[5];
    const float* W3 = (const float*)d_in[6];
    const float* b3 = (const float*)d_in[7];
    float* out = (float*)d_out;

    const int n = NNODES;
    const int E = in_sizes[1] / 2;
    const int* src = ei;
    const int* dst = ei + E;

    float* ws     = (float*)d_ws;
    float* dinv   = ws;                        // n f32
    int*   deg_i  = (int*)(ws + n);            // n i32
    int*   offs   = deg_i + n;                 // n i32 (END offsets)
    int*   bcnt   = offs + n;                  // 512 i32
    int*   bstart = bcnt + 512;                // 512 i32
    float* w23    = (float*)(bstart + 512);    // 72 f32 (+ pad to 80)
    __half* Wt    = (__half*)(w23 + 80);       // 80*WT_LD halves (pad to 11008)
    float* g2     = (float*)(Wt + 11008);      // n f32
    float* q      = g2 + n;                    // n f32
    int*   csr    = (int*)(q + n);             // E i32
    __half* msg   = (__half*)(csr + E);        // n*72 halves (14.4 MB)
    unsigned* bdata = (unsigned*)(msg + (size_t)n * 72);  // NB*BCAP u32 (7.2 MB)

    // ---- CSR build ----
    hipMemsetAsync(bcnt, 0, 512 * sizeof(int), stream);
    binA_kernel<<<(E + 1023) / 1024, 256, 0, stream>>>(src, dst, bcnt, bdata, E);
    prep_kernel<<<3, 1024, 0, stream>>>(bcnt, bstart, W2, b2, W3, w23, W1, Wt);
    binB2_kernel<<<NB, 512, 0, stream>>>(bcnt, bstart, bdata, deg_i, offs, dinv, csr, n);

    // ---- layer 1 transform via MFMA: msg = fp16( (x@W1)*dinv ) ----
    xform_mfma<<<1563, 256, 0, stream>>>(x, Wt, dinv, msg, n);

    // ---- fused layer-1 gather + ReLU + (W2*W3) contraction -> scalar per node ----
    gather_fused<71><<<2048, 256, 0, stream>>>((const __half2*)msg, csr, offs, deg_i, dinv, b1, w23, g2, n);

    // ---- collapsed layers 2+3: two scalar aggregations ----
    sgather_q<<<(n + 255) / 256, 256, 0, stream>>>(g2, csr, offs, deg_i, dinv, w23, q, n);
    sgather_out<<<(n + 255) / 256, 256, 0, stream>>>(q, csr, offs, deg_i, dinv, b3, out, n);
}

// Round 14
// 240.186 us; speedup vs baseline: 1.1434x; 1.1434x over previous
//
#include <hip/hip_runtime.h>
#include <hip/hip_fp16.h>

#define NNODES 100000
#define NB 196         // coarse buckets: node >> 9 (512 nodes each)
#define BSHIFT 9
#define BMASK 511
#define BCAP 9216      // per-bucket capacity (avg 8163, sigma ~90 -> +11.7 sigma)
#define WT_LD 136      // padded k-stride (halves) for transposed W1

typedef _Float16 half8 __attribute__((ext_vector_type(8)));
typedef float floatx4 __attribute__((ext_vector_type(4)));

// ---- phase A: coarse-bin edges; two LDS atomics/edge (R11-proven shape) ----
__global__ void binA_kernel(const int* __restrict__ src, const int* __restrict__ dst,
                            int* __restrict__ bcnt, unsigned* __restrict__ bdata, int E) {
    __shared__ int hist[NB];
    __shared__ int gb[NB];
    __shared__ int cur[NB];
    const int BATCH = 4096;  // 16 edges / thread
    for (int base = blockIdx.x * BATCH; base < E; base += gridDim.x * BATCH) {
        for (int i = threadIdx.x; i < NB; i += blockDim.x) hist[i] = 0;
        __syncthreads();
        int s[16], d[16];
        int cnt = 0;
        if (base + BATCH <= E) {  // full batch: int4 loads
#pragma unroll
            for (int q = 0; q < 4; ++q) {
                int4 sv = ((const int4*)(src + base))[q * 256 + threadIdx.x];
                int4 dv = ((const int4*)(dst + base))[q * 256 + threadIdx.x];
                s[cnt] = sv.x; d[cnt] = dv.x; atomicAdd(&hist[dv.x >> BSHIFT], 1); ++cnt;
                s[cnt] = sv.y; d[cnt] = dv.y; atomicAdd(&hist[dv.y >> BSHIFT], 1); ++cnt;
                s[cnt] = sv.z; d[cnt] = dv.z; atomicAdd(&hist[dv.z >> BSHIFT], 1); ++cnt;
                s[cnt] = sv.w; d[cnt] = dv.w; atomicAdd(&hist[dv.w >> BSHIFT], 1); ++cnt;
            }
        } else {
#pragma unroll
            for (int k = 0; k < 16; ++k) {
                int idx = base + k * 256 + threadIdx.x;
                if (idx < E) {
                    s[cnt] = src[idx];
                    d[cnt] = dst[idx];
                    atomicAdd(&hist[d[cnt] >> BSHIFT], 1);
                    ++cnt;
                }
            }
        }
        __syncthreads();
        for (int i = threadIdx.x; i < NB; i += blockDim.x) {
            int c = hist[i];
            gb[i] = (c > 0) ? atomicAdd(&bcnt[i], c) : 0;
            cur[i] = 0;
        }
        __syncthreads();
        for (int k = 0; k < cnt; ++k) {
            int b = d[k] >> BSHIFT;
            int lo = gb[b] + atomicAdd(&cur[b], 1);
            if (lo < BCAP)
                bdata[(size_t)b * BCAP + lo] = ((unsigned)s[k] << BSHIFT) | ((unsigned)d[k] & BMASK);
        }
        __syncthreads();
    }
}

// ---- fused prep: block 0 = bucket scan, block 1 = w23 fold, block 2 = W1 transpose/fp16 ----
__global__ __launch_bounds__(1024) void prep_kernel(
        const int* __restrict__ bcnt, int* __restrict__ bstart,
        const float* __restrict__ W2, const float* __restrict__ b2,
        const float* __restrict__ W3, float* __restrict__ w23,
        const float* __restrict__ W1, __half* __restrict__ Wt) {
    if (blockIdx.x == 0) {
        __shared__ int sh[NB];
        int t = threadIdx.x;
        if (t < NB) sh[t] = min(bcnt[t], BCAP);
        __syncthreads();
        if (t == 0) {
            int acc = 0;
            for (int i = 0; i < NB; ++i) { int v = sh[i]; sh[i] = acc; acc += v; }
        }
        __syncthreads();
        if (t < NB) bstart[t] = sh[t];
    } else if (blockIdx.x == 1) {
        int k = threadIdx.x;
        if (k < 71) {
            float a = 0.f;
            for (int j = 0; j < 82; ++j) a += W2[k * 82 + j] * W3[j];
            w23[k] = a;
        } else if (k == 71) {
            float a = 0.f;
            for (int j = 0; j < 82; ++j) a += b2[j] * W3[j];
            w23[71] = a;
        }
    } else {
        for (int i = threadIdx.x; i < 80 * WT_LD; i += blockDim.x) {
            int nn = i / WT_LD, k = i - nn * WT_LD;
            float v = (nn < 71 && k < 128) ? W1[k * 71 + nn] : 0.f;
            Wt[i] = __float2half(v);
        }
    }
}

// ---- phase B: per-bucket (512 nodes) LDS-cached hist + scan + CSR fill (R11 shape) ----
__global__ __launch_bounds__(1024) void binB2_kernel(
        const int* __restrict__ bcnt, const int* __restrict__ bstart,
        const unsigned* __restrict__ bdata,
        int* __restrict__ deg, int* __restrict__ end_off, float* __restrict__ dinv,
        int* __restrict__ csr, int n) {
    __shared__ unsigned edata[BCAP];   // 36 KB: bucket cached in LDS
    __shared__ int hist[512];
    __shared__ int cur[512];
    __shared__ int wsum[8];
    int b = blockIdx.x;
    int tid = threadIdx.x;
    int cnt = min(bcnt[b], BCAP);
    int base = bstart[b];
    const unsigned* p = bdata + (size_t)b * BCAP;
    if (tid < 512) hist[tid] = 0;
    __syncthreads();
    for (int i = tid; i < cnt; i += 1024) {
        unsigned e = p[i];
        edata[i] = e;
        atomicAdd(&hist[e & BMASK], 1);
    }
    __syncthreads();
    if (tid < 512) {  // 8-wave inclusive scan of hist
        int v = hist[tid];
        int lane = tid & 63;
        int incl = v;
#pragma unroll
        for (int off = 1; off < 64; off <<= 1) {
            int t = __shfl_up(incl, off);
            if (lane >= off) incl += t;
        }
        cur[tid] = incl;  // stash inclusive intra-wave prefix
        if (lane == 63) wsum[tid >> 6] = incl;
    }
    __syncthreads();
    if (tid == 0) {
        int acc = 0;
#pragma unroll
        for (int w = 0; w < 8; ++w) { int t = wsum[w]; wsum[w] = acc; acc += t; }
    }
    __syncthreads();
    if (tid < 512) {
        int v = hist[tid];
        int start = base + wsum[tid >> 6] + cur[tid] - v;  // exclusive prefix
        int node = (b << BSHIFT) + tid;
        if (node < n) {
            deg[node] = v;
            end_off[node] = start + v;
            dinv[node] = rsqrtf((float)v + 1.0f);
        }
        cur[tid] = start;
    }
    __syncthreads();
    for (int i = tid; i < cnt; i += 1024) {
        unsigned e = edata[i];
        int pos = atomicAdd(&cur[e & BMASK], 1);
        csr[pos] = (int)(e >> BSHIFT);
    }
}

// ---- MFMA transform: msg[row, 0..71] = half( (x[row,:128] @ W1) * scale[row] ) ----
__global__ __launch_bounds__(256) void xform_mfma(
        const float* __restrict__ x, const __half* __restrict__ Wt,
        const float* __restrict__ scale, __half* __restrict__ msg, int n) {
    __shared__ __half Wsh[80 * WT_LD];   // 21.25 KB
    {
        const uint4* sp = (const uint4*)Wt;
        uint4* dp = (uint4*)Wsh;
        for (int i = threadIdx.x; i < (80 * WT_LD * 2) / 16; i += blockDim.x) dp[i] = sp[i];
    }
    __syncthreads();
    int lane = threadIdx.x & 63;
    int m = lane & 15, q = lane >> 4;
    int gw = (blockIdx.x * blockDim.x + threadIdx.x) >> 6;
    int nw = (gridDim.x * blockDim.x) >> 6;
    int nrt = n >> 4;  // 16-row tiles (n % 16 == 0)
    for (int rt = gw; rt < nrt; rt += nw) {
        int rb = rt << 4;
        const float* xr = x + (size_t)(rb + m) * 128 + q * 8;
        floatx4 acc[5];
#pragma unroll
        for (int t = 0; t < 5; ++t) acc[t] = (floatx4){0.f, 0.f, 0.f, 0.f};
#pragma unroll
        for (int ks = 0; ks < 4; ++ks) {
            float4 f0 = *(const float4*)(xr + ks * 32);
            float4 f1 = *(const float4*)(xr + ks * 32 + 4);
            half8 a;
            a[0] = (_Float16)f0.x; a[1] = (_Float16)f0.y;
            a[2] = (_Float16)f0.z; a[3] = (_Float16)f0.w;
            a[4] = (_Float16)f1.x; a[5] = (_Float16)f1.y;
            a[6] = (_Float16)f1.z; a[7] = (_Float16)f1.w;
#pragma unroll
            for (int t = 0; t < 5; ++t) {
                half8 b = *(const half8*)&Wsh[(t * 16 + m) * WT_LD + ks * 32 + q * 8];
                acc[t] = __builtin_amdgcn_mfma_f32_16x16x32_f16(a, b, acc[t], 0, 0, 0);
            }
        }
        float sc[4];
#pragma unroll
        for (int r = 0; r < 4; ++r) sc[r] = scale[rb + q * 4 + r];
#pragma unroll
        for (int t = 0; t < 5; ++t) {
            int col = t * 16 + m;
            if (col < 72) {
#pragma unroll
                for (int r = 0; r < 4; ++r)
                    msg[(size_t)(rb + q * 4 + r) * 72 + col] = __float2half(acc[t][r] * sc[r]);
            }
        }
    }
}

// ---- fused gather + ReLU + w23 contraction: wave per node, 8-edge unroll (R10 shape) ----
template <int OC>
__global__ void gather_fused(const __half2* __restrict__ msg, const int* __restrict__ csr,
                             const int* __restrict__ end_off, const int* __restrict__ deg,
                             const float* __restrict__ dinv, const float* __restrict__ b,
                             const float* __restrict__ w23, float* __restrict__ g2, int n) {
    constexpr int OC2 = (OC + 1) / 2;
    int lane = threadIdx.x & 63;
    int wid = (blockIdx.x * blockDim.x + threadIdx.x) >> 6;
    int nwaves = (gridDim.x * blockDim.x) >> 6;
    bool act = lane < OC2;
    int c = lane << 1;
    float bx = (act && c < OC) ? b[c] : 0.f;
    float by = (act && c + 1 < OC) ? b[c + 1] : 0.f;
    float w0 = (act && c < OC) ? w23[c] : 0.f;
    float w1 = (act && c + 1 < OC) ? w23[c + 1] : 0.f;
    for (int node = wid; node < n; node += nwaves) {
        int end = end_off[node];
        int cnt = deg[node];
        int start = end - cnt;
        float ax0 = 0.f, ay0 = 0.f, ax1 = 0.f, ay1 = 0.f;
        float ax2 = 0.f, ay2 = 0.f, ax3 = 0.f, ay3 = 0.f;
        for (int base = 0; base < cnt; base += 64) {
            int rem = min(cnt - base, 64);
            int se = (lane < rem) ? csr[start + base + lane] : 0;
            int j = 0;
            for (; j + 7 < rem; j += 8) {
                int s0 = __shfl(se, j),     s1 = __shfl(se, j + 1);
                int s2 = __shfl(se, j + 2), s3 = __shfl(se, j + 3);
                int s4 = __shfl(se, j + 4), s5 = __shfl(se, j + 5);
                int s6 = __shfl(se, j + 6), s7 = __shfl(se, j + 7);
                if (act) {
                    float2 v0 = __half22float2(msg[(size_t)s0 * OC2 + lane]);
                    float2 v1 = __half22float2(msg[(size_t)s1 * OC2 + lane]);
                    float2 v2 = __half22float2(msg[(size_t)s2 * OC2 + lane]);
                    float2 v3 = __half22float2(msg[(size_t)s3 * OC2 + lane]);
                    float2 v4 = __half22float2(msg[(size_t)s4 * OC2 + lane]);
                    float2 v5 = __half22float2(msg[(size_t)s5 * OC2 + lane]);
                    float2 v6 = __half22float2(msg[(size_t)s6 * OC2 + lane]);
                    float2 v7 = __half22float2(msg[(size_t)s7 * OC2 + lane]);
                    ax0 += v0.x; ay0 += v0.y;  ax1 += v1.x; ay1 += v1.y;
                    ax2 += v2.x; ay2 += v2.y;  ax3 += v3.x; ay3 += v3.y;
                    ax0 += v4.x; ay0 += v4.y;  ax1 += v5.x; ay1 += v5.y;
                    ax2 += v6.x; ay2 += v6.y;  ax3 += v7.x; ay3 += v7.y;
                }
            }
            for (; j + 3 < rem; j += 4) {
                int s0 = __shfl(se, j),     s1 = __shfl(se, j + 1);
                int s2 = __shfl(se, j + 2), s3 = __shfl(se, j + 3);
                if (act) {
                    float2 v0 = __half22float2(msg[(size_t)s0 * OC2 + lane]);
                    float2 v1 = __half22float2(msg[(size_t)s1 * OC2 + lane]);
                    float2 v2 = __half22float2(msg[(size_t)s2 * OC2 + lane]);
                    float2 v3 = __half22float2(msg[(size_t)s3 * OC2 + lane]);
                    ax0 += v0.x; ay0 += v0.y;  ax1 += v1.x; ay1 += v1.y;
                    ax2 += v2.x; ay2 += v2.y;  ax3 += v3.x; ay3 += v3.y;
                }
            }
            for (; j < rem; ++j) {
                int s = __shfl(se, j);
                if (act) {
                    float2 v = __half22float2(msg[(size_t)s * OC2 + lane]);
                    ax0 += v.x; ay0 += v.y;
                }
            }
        }
        float dv = dinv[node];
        float p = 0.f;
        if (act) {
            float2 selfv = __half22float2(msg[(size_t)node * OC2 + lane]);
            float sx = ((ax0 + ax1) + (ax2 + ax3)) + selfv.x;
            float sy = ((ay0 + ay1) + (ay2 + ay3)) + selfv.y;
            float vx = fmaxf(dv * sx + bx, 0.f);   // ReLU
            float vy = fmaxf(dv * sy + by, 0.f);
            p = vx * w0 + vy * w1;
        }
#pragma unroll
        for (int off = 32; off > 0; off >>= 1) p += __shfl_down(p, off);
        if (lane == 0) g2[node] = dv * p;
    }
}

// ---- scalar gather 1: q[i] = dinv_i * ( dinv_i*(sum g2[src] + g2[i]) + bw ) ----
__global__ void sgather_q(const float* __restrict__ g2, const int* __restrict__ csr,
                          const int* __restrict__ end_off, const int* __restrict__ deg,
                          const float* __restrict__ dinv, const float* __restrict__ w23,
                          float* __restrict__ q, int n) {
    float bw = w23[71];
    int stride = gridDim.x * blockDim.x;
    for (int i = blockIdx.x * blockDim.x + threadIdx.x; i < n; i += stride) {
        int end = end_off[i];
        int cnt = deg[i];
        float acc = 0.f;
        for (int j = end - cnt; j < end; ++j) acc += g2[csr[j]];
        float dv = dinv[i];
        q[i] = dv * (dv * (acc + g2[i]) + bw);
    }
}

// ---- scalar gather 2: out[i] = dinv_i*(sum q[src] + q[i]) + b3 ----
__global__ void sgather_out(const float* __restrict__ q, const int* __restrict__ csr,
                            const int* __restrict__ end_off, const int* __restrict__ deg,
                            const float* __restrict__ dinv, const float* __restrict__ b3,
                            float* __restrict__ out, int n) {
    int stride = gridDim.x * blockDim.x;
    for (int i = blockIdx.x * blockDim.x + threadIdx.x; i < n; i += stride) {
        int end = end_off[i];
        int cnt = deg[i];
        float acc = 0.f;
        for (int j = end - cnt; j < end; ++j) acc += q[csr[j]];
        out[i] = dinv[i] * (acc + q[i]) + b3[0];
    }
}

extern "C" void kernel_launch(void* const* d_in, const int* in_sizes, int n_in,
                              void* d_out, int out_size, void* d_ws, size_t ws_size,
                              hipStream_t stream) {
    const float* x  = (const float*)d_in[0];
    const int*   ei = (const int*)d_in[1];
    const float* W1 = (const float*)d_in[2];
    const float* b1 = (const float*)d_in[3];
    const float* W2 = (const float*)d_in[4];
    const float* b2 = (const float*)d_in[5];
    const float* W3 = (const float*)d_in[6];
    const float* b3 = (const float*)d_in[7];
    float* out = (float*)d_out;

    const int n = NNODES;
    const int E = in_sizes[1] / 2;
    const int* src = ei;
    const int* dst = ei + E;

    float* ws     = (float*)d_ws;
    float* dinv   = ws;                        // n f32
    int*   deg_i  = (int*)(ws + n);            // n i32
    int*   offs   = deg_i + n;                 // n i32 (END offsets)
    int*   bcnt   = offs + n;                  // 256 i32
    int*   bstart = bcnt + 256;                // 256 i32
    float* w23    = (float*)(bstart + 256);    // 72 f32 (+ pad to 80)
    __half* Wt    = (__half*)(w23 + 80);       // 80*WT_LD halves (pad to 11008)
    float* g2     = (float*)(Wt + 11008);      // n f32
    float* q      = g2 + n;                    // n f32
    int*   csr    = (int*)(q + n);             // E i32
    __half* msg   = (__half*)(csr + E);        // n*72 halves (14.4 MB)
    unsigned* bdata = (unsigned*)(msg + (size_t)n * 72);  // NB*BCAP u32 (7.2 MB)

    // ---- CSR build ----
    hipMemsetAsync(bcnt, 0, 256 * sizeof(int), stream);
    binA_kernel<<<(E + 4095) / 4096, 256, 0, stream>>>(src, dst, bcnt, bdata, E);
    prep_kernel<<<3, 1024, 0, stream>>>(bcnt, bstart, W2, b2, W3, w23, W1, Wt);
    binB2_kernel<<<NB, 1024, 0, stream>>>(bcnt, bstart, bdata, deg_i, offs, dinv, csr, n);

    // ---- layer 1 transform via MFMA: msg = fp16( (x@W1)*dinv ) ----
    xform_mfma<<<1563, 256, 0, stream>>>(x, Wt, dinv, msg, n);

    // ---- fused layer-1 gather + ReLU + (W2*W3) contraction -> scalar per node ----
    gather_fused<71><<<2048, 256, 0, stream>>>((const __half2*)msg, csr, offs, deg_i, dinv, b1, w23, g2, n);

    // ---- collapsed layers 2+3: two scalar aggregations ----
    sgather_q<<<(n + 255) / 256, 256, 0, stream>>>(g2, csr, offs, deg_i, dinv, w23, q, n);
    sgather_out<<<(n + 255) / 256, 256, 0, stream>>>(q, csr, offs, deg_i, dinv, b3, out, n);
}